// Round 15
// baseline (63.856 us; speedup 1.0000x reference)
//
#include <hip/hip_runtime.h>

#define NF 64

// ws float offsets
#define OFF_U       8194       // 128
#define OFF_NPG     9216       // 8*2048 partial row counts (g side)
#define OFF_NPP     25600      // 8*2048 partial col counts (p side)
#define OFF_HA_G    41984      // 131072
#define OFF_HA_P    173056
#define OFF_HB_G    304128
#define OFF_HB_P    435200
#define OFF_EG      566272
#define OFF_EP      697344
#define OFF_AFRAG   2162688    // 2M ushorts (A frags, both sides)
#define OFF_HFA     3211264    // 1M ushorts (h frags hi/lo x side), buffer A
#define OFF_HFB     3735552    // buffer B
#define OFF_WF      4259840    // 196608 ushorts: W frags hi/lo, 12 matrices
#define OFF_HPART   4358144    // 256*64 floats
#define OFF_CNT     4374528    // 1 int (completion counter, zeroed by k_prep)
#define OFF_RD      4374592    // 2048 floats (per-row readout dots)

typedef __attribute__((ext_vector_type(8))) short bf16x8;
typedef __attribute__((ext_vector_type(4))) float f32x4;

static __device__ __forceinline__ float wave_sum(float v) {
    for (int off = 32; off; off >>= 1) v += __shfl_down(v, off, 64);
    return v;
}
static __device__ __forceinline__ float wave_max(float v) {
    for (int off = 32; off; off >>= 1) v = fmaxf(v, __shfl_down(v, off, 64));
    return v;
}
static __device__ __forceinline__ unsigned short f2bf(float x) {   // RNE bf16
    unsigned u = __float_as_uint(x);
    return (unsigned short)((u + 0x7FFFu + ((u >> 16) & 1u)) >> 16);
}

// ---------------- K1: tile load + private-slot counts + A-frags + wpack/U ride-along ----------------
__global__ __launch_bounds__(256) void k_prep(const float* __restrict__ obs,
        float* __restrict__ ws,
        const float* __restrict__ Wm_g, const float* __restrict__ Wu_g,
        const float* __restrict__ Wm_p, const float* __restrict__ Wu_p,
        const float* __restrict__ Wee_g, const float* __restrict__ Wef_g,
        const float* __restrict__ Wee_p, const float* __restrict__ Wef_p) {
    __shared__ float tile[64][65];
    __shared__ float cc[4][64];
    int b = blockIdx.y, t = threadIdx.x;
    if (blockIdx.x == 0 && b == 0 && t == 0) ((int*)(ws + OFF_CNT))[0] = 0;
    int tg = blockIdx.x >> 3, tp = blockIdx.x & 7;
    int g0 = tg * 64, p0 = tp * 64;
    int c = t & 63, q = t >> 6;        // q = wave id
    const float* src = obs + ((size_t)b * 512 + g0) * 512 + p0;
    float colcnt = 0.f;
#pragma unroll
    for (int i = 0; i < 16; ++i) {
        int r = q + 4 * i;
        float v = src[(size_t)r * 512 + c];
        tile[r][c] = v;
        bool nz = (v != 0.f);
        colcnt += nz ? 1.f : 0.f;
        unsigned long long mask = __ballot(nz);
        if (c == 0)
            ws[OFF_NPG + tp * 2048 + b * 512 + g0 + r] = (float)__popcll(mask);
    }
    cc[q][c] = colcnt;
    __syncthreads();
    if (q == 0)
        ws[OFF_NPP + tg * 2048 + b * 512 + p0 + c] =
            cc[0][c] + cc[1][c] + cc[2][c] + cc[3][c];
    // A-frag emission, both sides (R8-verified layout)
    int ri = c & 15, kq = c >> 4;
    unsigned short* afg = (unsigned short*)(ws + OFF_AFRAG);
    unsigned short* afp = afg + 1048576;
    int rt_g = b * 32 + tg * 4 + q;
    int rt_p = b * 32 + tp * 4 + q;
#pragma unroll
    for (int ks2 = 0; ks2 < 2; ++ks2) {
        int ks_g = tp * 2 + ks2;
        int ks_p = tg * 2 + ks2;
        bf16x8 og, op;
#pragma unroll
        for (int i = 0; i < 8; ++i) {
            og[i] = (short)f2bf(tile[q * 16 + ri][ks2 * 32 + kq * 8 + i]);
            op[i] = (short)f2bf(tile[ks2 * 32 + kq * 8 + i][q * 16 + ri]);
        }
        *(bf16x8*)(afg + ((size_t)(rt_g * 16 + ks_g) * 64 + c) * 8) = og;
        *(bf16x8*)(afp + ((size_t)(rt_p * 16 + ks_p) * 64 + c) * 8) = op;
    }
    // ride-along tasks
    int lin = b * 64 + blockIdx.x;
    if (lin < 48) {   // weight pack: 12 mats x 4 ks2
        int mat = lin >> 2, ks2 = lin & 3;
        int side = mat / 6, m = (mat / 3) & 1, layer = mat % 3;
        const float* W = (side ? (m ? Wu_p : Wm_p) : (m ? Wu_g : Wm_g)) + layer * 8192;
        int ftq = t >> 6, lane = t & 63;
        int f = ftq * 16 + (lane & 15);
        int kbase = ks2 * 32 + ((lane >> 4) & 3) * 8;
        bf16x8 oh, ol;
#pragma unroll
        for (int i = 0; i < 8; ++i) {
            float v = W[(kbase + i) * 64 + f];
            unsigned short hi = f2bf(v);
            oh[i] = (short)hi;
            ol[i] = (short)f2bf(v - __uint_as_float((unsigned)hi << 16));
        }
        unsigned short* WF = (unsigned short*)(ws + OFF_WF);
        *(bf16x8*)(WF + (((size_t)(mat * 2 + 0) * 4 + ks2) * 4 + ftq) * 512 + lane * 8) = oh;
        *(bf16x8*)(WF + (((size_t)(mat * 2 + 1) * 4 + ks2) * 4 + ftq) * 512 + lane * 8) = ol;
    } else if (lin == 48 && t < 128) {   // U precompute
        int side = t >> 6, f = t & 63;
        const float* Wee = side ? Wee_p : Wee_g;
        const float* Wef = side ? Wef_p : Wef_g;
        float u = 0.f;
#pragma unroll
        for (int e = 0; e < 63; ++e) u += fmaxf(Wee[e], 0.f) * Wef[e * 64 + f];
        ws[OFF_U + t] = u;
    }
}

// ---------------- K2: fused init + LAYER 0 (rank-1 agg, R14-verified) ----------------
__global__ __launch_bounds__(256) void k_init_l0(float* __restrict__ ws,
        const float* __restrict__ Wi_g, const float* __restrict__ Wi_p,
        const float* __restrict__ Wef_g, const float* __restrict__ Wef_p) {
    __shared__ float normall[2048];
    __shared__ float nopp[512];
    __shared__ float redm[4];
    __shared__ float sred[4][16], wred[4][16];
    __shared__ float s_l[16], w_l[16];
    __shared__ float xe[16][68], xh[16][68], xa[16][68], xm[16][68];
    int bid = blockIdx.x, side = bid >> 7, rt = bid & 127;
    int lr0 = rt * 16, b = rt >> 5;
    int t = threadIdx.x, lane = t & 63, w = t >> 6;
    const float* pown = ws + (side ? OFF_NPP : OFF_NPG);
    const float* popp = ws + (side ? OFF_NPG : OFF_NPP) + b * 512;
#pragma unroll
    for (int i = 0; i < 8; ++i) {
        int r = t + 256 * i;
        float s = 0.f;
#pragma unroll
        for (int j = 0; j < 8; ++j) s += pown[j * 2048 + r];
        normall[r] = s;
    }
#pragma unroll
    for (int i = 0; i < 2; ++i) {
        int r = t + 256 * i;
        float s = 0.f;
#pragma unroll
        for (int j = 0; j < 8; ++j) s += popp[j * 2048 + r];
        nopp[r] = s;
    }
    __syncthreads();
    float m = 0.f;
#pragma unroll
    for (int i = 0; i < 8; ++i) m = fmaxf(m, normall[t + 256 * i]);
    m = wave_max(m);
    if (lane == 0) redm[w] = m;
    const unsigned short* af = (const unsigned short*)(ws + OFF_AFRAG)
                               + (size_t)side * 1048576;
    int kq = lane >> 4;
    float sacc = 0.f, wacc = 0.f;
#pragma unroll
    for (int kk = 0; kk < 4; ++kk) {
        int ks = w * 4 + kk;
        bf16x8 a = *(const bf16x8*)(af + ((size_t)(rt * 16 + ks) * 64 + lane) * 8);
#pragma unroll
        for (int i = 0; i < 8; ++i)
            if (a[i] != 0) {
                float nv = nopp[ks * 32 + kq * 8 + i];
                sacc += nv;
                float av = __uint_as_float((unsigned)(unsigned short)a[i] << 16);
                wacc += av * nv;
            }
    }
    sacc += __shfl_xor(sacc, 16, 64);
    sacc += __shfl_xor(sacc, 32, 64);
    wacc += __shfl_xor(wacc, 16, 64);
    wacc += __shfl_xor(wacc, 32, 64);
    if (lane < 16) { sred[w][lane] = sacc; wred[w][lane] = wacc; }
    __syncthreads();
    float mxs = fmaxf(fmaxf(redm[0], redm[1]), fmaxf(redm[2], redm[3]));
    if (t < 16) {
        s_l[t] = (sred[0][t] + sred[1][t] + sred[2][t] + sred[3][t]) * (1.f / 512.f);
        w_l[t] = (wred[0][t] + wred[1][t] + wred[2][t] + wred[3][t]) * (1.f / 512.f);
    }
    __syncthreads();
    float maxnf = fmaxf(mxs, 1.f);
    const float* Wi_own = side ? Wi_p : Wi_g;
    const float* Wi_opp = side ? Wi_g : Wi_p;
    const float* Wef = side ? Wef_p : Wef_g;
    int ff = lane;
    float Uv = ws[OFF_U + side * 64 + ff];
    float wef63 = Wef[63 * 64 + ff];
    float wiv = Wi_own[ff];
    float wio = fmaxf(Wi_opp[ff], 0.f);
#pragma unroll
    for (int q = 0; q < 4; ++q) {
        int r = w * 4 + q, lr = lr0 + r;
        float norm = normall[lr];
        float nf1 = norm > 0.f ? norm : 1.f;
        float h = fmaxf(norm * (1.f / 512.f) * wiv, 0.f);
        xh[r][ff] = h;
        float A = s_l[r] / nf1;
        float C = norm / maxnf;
        float e = fmaxf(A * Uv + C * wef63, 0.f);
        ws[(side ? OFF_EP : OFF_EG) + (size_t)lr * 64 + ff] = e;
        xe[r][ff] = e;
        xa[r][ff] = w_l[r] * wio / nf1;     // exact rank-1 layer-0 aggregation
    }
    __syncthreads();

    int ft = __builtin_amdgcn_readfirstlane(w);
    const unsigned short* WF = (const unsigned short*)(ws + OFF_WF);
    int mat_msg = (side * 2 + 0) * 3 + 0;
    int mat_upd = (side * 2 + 1) * 3 + 0;
    int ar = lane & 15, koff = ((lane >> 4) & 3) * 8;

    f32x4 mc = {0.f, 0.f, 0.f, 0.f};
#pragma unroll
    for (int ks2 = 0; ks2 < 4; ++ks2) {
        const float* src = (ks2 < 2) ? &xa[ar][ks2 * 32 + koff]
                                     : &xe[ar][(ks2 - 2) * 32 + koff];
        float4 lo4 = *(const float4*)src;
        float4 hi4 = *(const float4*)(src + 4);
        bf16x8 xhf, xlf;
        {
            float xv[8] = {lo4.x, lo4.y, lo4.z, lo4.w, hi4.x, hi4.y, hi4.z, hi4.w};
#pragma unroll
            for (int i = 0; i < 8; ++i) {
                unsigned short hh = f2bf(xv[i]);
                xhf[i] = (short)hh;
                xlf[i] = (short)f2bf(xv[i] - __uint_as_float((unsigned)hh << 16));
            }
        }
        bf16x8 wh = *(const bf16x8*)(WF + (((size_t)(mat_msg * 2 + 0) * 4 + ks2) * 4 + ft) * 512 + lane * 8);
        bf16x8 wl = *(const bf16x8*)(WF + (((size_t)(mat_msg * 2 + 1) * 4 + ks2) * 4 + ft) * 512 + lane * 8);
        mc = __builtin_amdgcn_mfma_f32_16x16x32_bf16(xhf, wh, mc, 0, 0, 0);
        mc = __builtin_amdgcn_mfma_f32_16x16x32_bf16(xlf, wh, mc, 0, 0, 0);
        mc = __builtin_amdgcn_mfma_f32_16x16x32_bf16(xhf, wl, mc, 0, 0, 0);
    }
    {
        int c = lane & 15, rq = (lane >> 4) * 4, f = ft * 16 + c;
#pragma unroll
        for (int j = 0; j < 4; ++j) xm[rq + j][f] = fmaxf(mc[j], 0.f);
    }
    __syncthreads();

    f32x4 uc = {0.f, 0.f, 0.f, 0.f};
#pragma unroll
    for (int ks2 = 0; ks2 < 4; ++ks2) {
        const float* src = (ks2 < 2) ? &xh[ar][ks2 * 32 + koff]
                                     : &xm[ar][(ks2 - 2) * 32 + koff];
        float4 lo4 = *(const float4*)src;
        float4 hi4 = *(const float4*)(src + 4);
        bf16x8 xhf, xlf;
        {
            float xv[8] = {lo4.x, lo4.y, lo4.z, lo4.w, hi4.x, hi4.y, hi4.z, hi4.w};
#pragma unroll
            for (int i = 0; i < 8; ++i) {
                unsigned short hh = f2bf(xv[i]);
                xhf[i] = (short)hh;
                xlf[i] = (short)f2bf(xv[i] - __uint_as_float((unsigned)hh << 16));
            }
        }
        bf16x8 wh = *(const bf16x8*)(WF + (((size_t)(mat_upd * 2 + 0) * 4 + ks2) * 4 + ft) * 512 + lane * 8);
        bf16x8 wl = *(const bf16x8*)(WF + (((size_t)(mat_upd * 2 + 1) * 4 + ks2) * 4 + ft) * 512 + lane * 8);
        uc = __builtin_amdgcn_mfma_f32_16x16x32_bf16(xhf, wh, uc, 0, 0, 0);
        uc = __builtin_amdgcn_mfma_f32_16x16x32_bf16(xlf, wh, uc, 0, 0, 0);
        uc = __builtin_amdgcn_mfma_f32_16x16x32_bf16(xhf, wl, uc, 0, 0, 0);
    }
    {   // relu -> HB f32 + HFB frags
        int c = lane & 15, rq = (lane >> 4) * 4, f = ft * 16 + c;
        int hout = side ? OFF_HB_P : OFF_HB_G;
        unsigned short hi4[4], lo4b[4];
#pragma unroll
        for (int j = 0; j < 4; ++j) {
            float hv = fmaxf(uc[j], 0.f);
            ws[hout + (size_t)(lr0 + rq + j) * 64 + f] = hv;
            unsigned short hh = f2bf(hv);
            hi4[j] = hh;
            lo4b[j] = f2bf(hv - __uint_as_float((unsigned)hh << 16));
        }
        int k0 = (rt & 31) * 16 + rq;
        int ks_h = k0 >> 5;
        int lane2 = (f & 15) | (((k0 >> 3) & 3) << 4);
        size_t fidx = (((size_t)(b * 4 + ft) * 16 + ks_h) * 64 + lane2) * 8 + (k0 & 7);
        unsigned short* hf = (unsigned short*)(ws + OFF_HFB) + (size_t)side * 2 * 262144;
        uint2 vh, vl;
        vh.x = (unsigned)hi4[0] | ((unsigned)hi4[1] << 16);
        vh.y = (unsigned)hi4[2] | ((unsigned)hi4[3] << 16);
        vl.x = (unsigned)lo4b[0] | ((unsigned)lo4b[1] << 16);
        vl.y = (unsigned)lo4b[2] | ((unsigned)lo4b[3] << 16);
        *(uint2*)(hf + fidx) = vh;
        *(uint2*)(hf + 262144 + fidx) = vl;
    }
}

// ---------------- K3: full-MFMA layer; L2 (do_pool) also does last-block pool+readout ----------------
__global__ __launch_bounds__(256) void k_layer(float* __restrict__ ws, int layer,
        int hin_g, int hin_p, int hout_g, int hout_p, int fin, int fout, int do_pool,
        const float* __restrict__ Wpg, const float* __restrict__ Wpp,
        const float* __restrict__ Wro, const float* __restrict__ bro,
        float* __restrict__ out) {
    __shared__ float xe[16][68], xh[16][68], xa[16][68], xm[16][68];
    __shared__ float nrm16[16];
    __shared__ float psum[4][64];
    __shared__ float rds[16][64];
    __shared__ float hp2[128];
    __shared__ float c1v[4];
    __shared__ int lastflag;
    int bid = blockIdx.x, side = bid >> 7, rt = bid & 127;
    int lr0 = rt * 16, b = rt >> 5;
    int t = threadIdx.x, lane = t & 63;
    int ft = __builtin_amdgcn_readfirstlane(t >> 6);

    {   // stage e and h_self tiles + 16 row-norms
        int r = t >> 4, c4 = (t & 15) * 4;
        *(float4*)&xe[r][c4] = *(const float4*)(ws + (side ? OFF_EP : OFF_EG)
                                                + (size_t)(lr0 + r) * 64 + c4);
        *(float4*)&xh[r][c4] = *(const float4*)(ws + (side ? hin_p : hin_g)
                                                + (size_t)(lr0 + r) * 64 + c4);
        if (t < 16) {
            const float* po = ws + (side ? OFF_NPP : OFF_NPG) + lr0 + t;
            float s = 0.f;
#pragma unroll
            for (int j = 0; j < 8; ++j) s += po[j * 2048];
            nrm16[t] = fmaxf(s, 1.f);
        }
    }
    __syncthreads();

    // agg via MFMA
    const unsigned short* af = (const unsigned short*)(ws + OFF_AFRAG)
                               + (size_t)side * 1048576;
    const unsigned short* hfh = (const unsigned short*)(ws + fin)
                                + (size_t)(1 - side) * 2 * 262144;
    const unsigned short* hfl = hfh + 262144;
    f32x4 acc = {0.f, 0.f, 0.f, 0.f};
#pragma unroll
    for (int ks = 0; ks < 16; ++ks) {
        bf16x8 a = *(const bf16x8*)(af + ((size_t)(rt * 16 + ks) * 64 + lane) * 8);
        size_t bi = ((((size_t)b * 4 + ft) * 16 + ks) * 64 + lane) * 8;
        bf16x8 bh = *(const bf16x8*)(hfh + bi);
        bf16x8 bl = *(const bf16x8*)(hfl + bi);
        acc = __builtin_amdgcn_mfma_f32_16x16x32_bf16(a, bh, acc, 0, 0, 0);
        acc = __builtin_amdgcn_mfma_f32_16x16x32_bf16(a, bl, acc, 0, 0, 0);
    }
    {   // normalize -> x_agg
        int c = lane & 15, rq = (lane >> 4) * 4, f = ft * 16 + c;
#pragma unroll
        for (int j = 0; j < 4; ++j)
            xa[rq + j][f] = acc[j] / nrm16[rq + j];
    }
    __syncthreads();

    const unsigned short* WF = (const unsigned short*)(ws + OFF_WF);
    int mat_msg = (side * 2 + 0) * 3 + layer;
    int mat_upd = (side * 2 + 1) * 3 + layer;
    int ar = lane & 15, koff = ((lane >> 4) & 3) * 8;

    // msg GEMM: [agg | e] @ Wm
    f32x4 mc = {0.f, 0.f, 0.f, 0.f};
#pragma unroll
    for (int ks2 = 0; ks2 < 4; ++ks2) {
        const float* src = (ks2 < 2) ? &xa[ar][ks2 * 32 + koff]
                                     : &xe[ar][(ks2 - 2) * 32 + koff];
        float4 lo4 = *(const float4*)src;
        float4 hi4 = *(const float4*)(src + 4);
        bf16x8 xhf, xlf;
        {
            float xv[8] = {lo4.x, lo4.y, lo4.z, lo4.w, hi4.x, hi4.y, hi4.z, hi4.w};
#pragma unroll
            for (int i = 0; i < 8; ++i) {
                unsigned short hh = f2bf(xv[i]);
                xhf[i] = (short)hh;
                xlf[i] = (short)f2bf(xv[i] - __uint_as_float((unsigned)hh << 16));
            }
        }
        bf16x8 wh = *(const bf16x8*)(WF + (((size_t)(mat_msg * 2 + 0) * 4 + ks2) * 4 + ft) * 512 + lane * 8);
        bf16x8 wl = *(const bf16x8*)(WF + (((size_t)(mat_msg * 2 + 1) * 4 + ks2) * 4 + ft) * 512 + lane * 8);
        mc = __builtin_amdgcn_mfma_f32_16x16x32_bf16(xhf, wh, mc, 0, 0, 0);
        mc = __builtin_amdgcn_mfma_f32_16x16x32_bf16(xlf, wh, mc, 0, 0, 0);
        mc = __builtin_amdgcn_mfma_f32_16x16x32_bf16(xhf, wl, mc, 0, 0, 0);
    }
    {
        int c = lane & 15, rq = (lane >> 4) * 4, f = ft * 16 + c;
#pragma unroll
        for (int j = 0; j < 4; ++j) xm[rq + j][f] = fmaxf(mc[j], 0.f);
    }
    __syncthreads();

    // upd GEMM: [h_self | m] @ Wu
    f32x4 uc = {0.f, 0.f, 0.f, 0.f};
#pragma unroll
    for (int ks2 = 0; ks2 < 4; ++ks2) {
        const float* src = (ks2 < 2) ? &xh[ar][ks2 * 32 + koff]
                                     : &xm[ar][(ks2 - 2) * 32 + koff];
        float4 lo4 = *(const float4*)src;
        float4 hi4 = *(const float4*)(src + 4);
        bf16x8 xhf, xlf;
        {
            float xv[8] = {lo4.x, lo4.y, lo4.z, lo4.w, hi4.x, hi4.y, hi4.z, hi4.w};
#pragma unroll
            for (int i = 0; i < 8; ++i) {
                unsigned short hh = f2bf(xv[i]);
                xhf[i] = (short)hh;
                xlf[i] = (short)f2bf(xv[i] - __uint_as_float((unsigned)hh << 16));
            }
        }
        bf16x8 wh = *(const bf16x8*)(WF + (((size_t)(mat_upd * 2 + 0) * 4 + ks2) * 4 + ft) * 512 + lane * 8);
        bf16x8 wl = *(const bf16x8*)(WF + (((size_t)(mat_upd * 2 + 1) * 4 + ks2) * 4 + ft) * 512 + lane * 8);
        uc = __builtin_amdgcn_mfma_f32_16x16x32_bf16(xhf, wh, uc, 0, 0, 0);
        uc = __builtin_amdgcn_mfma_f32_16x16x32_bf16(xlf, wh, uc, 0, 0, 0);
        uc = __builtin_amdgcn_mfma_f32_16x16x32_bf16(xhf, wl, uc, 0, 0, 0);
    }
    {   // relu -> hout f32 + vectorized hfrag
        int c = lane & 15, rq = (lane >> 4) * 4, f = ft * 16 + c;
        int hout = side ? hout_p : hout_g;
        float s4 = 0.f;
        float hvv[4];
        unsigned short hi4[4], lo4[4];
#pragma unroll
        for (int j = 0; j < 4; ++j) {
            float hv = fmaxf(uc[j], 0.f);
            hvv[j] = hv;
            ws[hout + (size_t)(lr0 + rq + j) * 64 + f] = hv;
            unsigned short hh = f2bf(hv);
            hi4[j] = hh;
            lo4[j] = f2bf(hv - __uint_as_float((unsigned)hh << 16));
            s4 += hv;
        }
        int k0 = (rt & 31) * 16 + rq;
        int ks_h = k0 >> 5;
        int lane2 = (f & 15) | (((k0 >> 3) & 3) << 4);
        size_t fidx = (((size_t)(b * 4 + ft) * 16 + ks_h) * 64 + lane2) * 8 + (k0 & 7);
        unsigned short* hf = (unsigned short*)(ws + fout) + (size_t)side * 2 * 262144;
        uint2 vh, vl;
        vh.x = (unsigned)hi4[0] | ((unsigned)hi4[1] << 16);
        vh.y = (unsigned)hi4[2] | ((unsigned)hi4[3] << 16);
        vl.x = (unsigned)lo4[0] | ((unsigned)lo4[1] << 16);
        vl.y = (unsigned)lo4[2] | ((unsigned)lo4[3] << 16);
        *(uint2*)(hf + fidx) = vh;
        *(uint2*)(hf + 262144 + fidx) = vl;

        if (do_pool) {
            // pool partial + per-row readout dots (g-side rows feed the output)
            float wro64 = Wro[64 + f];
            psum[lane >> 4][f] = s4;
#pragma unroll
            for (int j = 0; j < 4; ++j) rds[rq + j][f] = hvv[j] * wro64;
            __syncthreads();
            if (t < 64)
                ws[OFF_HPART + bid * 64 + t] =
                    psum[0][t] + psum[1][t] + psum[2][t] + psum[3][t];
            if (side == 0 && t < 16) {
                float s = 0.f;
#pragma unroll
                for (int k = 0; k < 64; ++k) s += rds[t][k];
                ws[OFF_RD + lr0 + t] = s;
            }
            // completion protocol: release fence + counter; last block reads all
            __builtin_amdgcn_fence(__ATOMIC_RELEASE, "agent");
            __syncthreads();
            if (t == 0) {
                int old = __hip_atomic_fetch_add((int*)(ws + OFF_CNT), 1,
                                                 __ATOMIC_ACQ_REL, __HIP_MEMORY_SCOPE_AGENT);
                lastflag = (old == 255) ? 1 : 0;
            }
            __syncthreads();
            if (lastflag) {
                __builtin_amdgcn_fence(__ATOMIC_ACQUIRE, "agent");
                for (int b2 = 0; b2 < 4; ++b2) {
                    if (t < 128) {
                        int sd = t >> 6, k = t & 63;
                        const float* qq = ws + OFF_HPART + (size_t)(sd * 128 + b2 * 32) * 64 + k;
                        float s = 0.f;
#pragma unroll
                        for (int i = 0; i < 32; ++i) s += qq[i * 64];
                        hp2[t] = s;
                    }
                    __syncthreads();
                    if (t < 64) {
                        float vg = 0.f, vp = 0.f;
#pragma unroll 4
                        for (int k = 0; k < 64; ++k) {
                            vg += (hp2[k] * (1.f / 512.f)) * Wpg[k * 64 + t];
                            vp += (hp2[64 + k] * (1.f / 512.f)) * Wpp[k * 64 + t];
                        }
                        float hv2 = fmaxf(vg + vp, 0.f);
                        float cc2 = wave_sum(hv2 * Wro[t]);
                        if (t == 0) c1v[b2] = cc2 + bro[0];
                    }
                    __syncthreads();
                }
#pragma unroll
                for (int i = 0; i < 8; ++i) {
                    int idx = t + 256 * i;
                    out[idx] = c1v[idx >> 9] + ws[OFF_RD + idx];
                }
            }
        }
    }
}

extern "C" void kernel_launch(void* const* d_in, const int* in_sizes, int n_in,
                              void* d_out, int out_size, void* d_ws, size_t ws_size,
                              hipStream_t stream) {
    const float* obs   = (const float*)d_in[0];
    const float* Wi_g  = (const float*)d_in[1];
    const float* Wi_p  = (const float*)d_in[2];
    const float* Wee_g = (const float*)d_in[3];
    const float* Wef_g = (const float*)d_in[4];
    const float* Wee_p = (const float*)d_in[5];
    const float* Wef_p = (const float*)d_in[6];
    const float* Wm_g  = (const float*)d_in[7];
    const float* Wu_g  = (const float*)d_in[8];
    const float* Wm_p  = (const float*)d_in[9];
    const float* Wu_p  = (const float*)d_in[10];
    const float* Wpg   = (const float*)d_in[11];
    const float* Wpp   = (const float*)d_in[12];
    const float* Wro   = (const float*)d_in[13];
    const float* bro   = (const float*)d_in[14];
    float* ws  = (float*)d_ws;
    float* out = (float*)d_out;

    k_prep<<<dim3(64, 4), 256, 0, stream>>>(obs, ws, Wm_g, Wu_g, Wm_p, Wu_p,
                                            Wee_g, Wef_g, Wee_p, Wef_p);
    k_init_l0<<<256, 256, 0, stream>>>(ws, Wi_g, Wi_p, Wef_g, Wef_p);

    k_layer<<<256, 256, 0, stream>>>(ws, 1, OFF_HB_G, OFF_HB_P, OFF_HA_G, OFF_HA_P,
                                     OFF_HFB, OFF_HFA, 0, Wpg, Wpp, Wro, bro, out);
    k_layer<<<256, 256, 0, stream>>>(ws, 2, OFF_HA_G, OFF_HA_P, OFF_HB_G, OFF_HB_P,
                                     OFF_HFA, OFF_HFB, 1, Wpg, Wpp, Wro, bro, out);
}

// Round 16
// 46.801 us; speedup vs baseline: 1.3644x; 1.3644x over previous
//
#include <hip/hip_runtime.h>

#define NF 64

// ws float offsets
#define OFF_U       8194       // 128
#define OFF_NPG     9216       // 8*2048 partial row counts (g side)
#define OFF_NPP     25600      // 8*2048 partial col counts (p side)
#define OFF_HA_G    41984      // 131072
#define OFF_HA_P    173056
#define OFF_HB_G    304128
#define OFF_HB_P    435200
#define OFF_EG      566272
#define OFF_EP      697344
#define OFF_AFRAG   2162688    // 2M ushorts (A frags, both sides)
#define OFF_HFA     3211264    // 1M ushorts (h frags hi/lo x side), buffer A
#define OFF_HFB     3735552    // buffer B
#define OFF_WF      4259840    // 196608 ushorts: W frags hi/lo, 12 matrices
#define OFF_HPART   4358144    // 256*64 floats

typedef __attribute__((ext_vector_type(8))) short bf16x8;
typedef __attribute__((ext_vector_type(4))) float f32x4;

static __device__ __forceinline__ float wave_sum(float v) {
    for (int off = 32; off; off >>= 1) v += __shfl_down(v, off, 64);
    return v;
}
static __device__ __forceinline__ float wave_max(float v) {
    for (int off = 32; off; off >>= 1) v = fmaxf(v, __shfl_down(v, off, 64));
    return v;
}
static __device__ __forceinline__ unsigned short f2bf(float x) {   // RNE bf16
    unsigned u = __float_as_uint(x);
    return (unsigned short)((u + 0x7FFFu + ((u >> 16) & 1u)) >> 16);
}

// ---------------- K1: tile load + private-slot counts + A-frags + wpack/U ride-along ----------------
__global__ __launch_bounds__(256) void k_prep(const float* __restrict__ obs,
        float* __restrict__ ws,
        const float* __restrict__ Wm_g, const float* __restrict__ Wu_g,
        const float* __restrict__ Wm_p, const float* __restrict__ Wu_p,
        const float* __restrict__ Wee_g, const float* __restrict__ Wef_g,
        const float* __restrict__ Wee_p, const float* __restrict__ Wef_p) {
    __shared__ float tile[64][65];
    __shared__ float cc[4][64];
    int b = blockIdx.y, t = threadIdx.x;
    int tg = blockIdx.x >> 3, tp = blockIdx.x & 7;
    int g0 = tg * 64, p0 = tp * 64;
    int c = t & 63, q = t >> 6;        // q = wave id
    const float* src = obs + ((size_t)b * 512 + g0) * 512 + p0;
    float colcnt = 0.f;
#pragma unroll
    for (int i = 0; i < 16; ++i) {
        int r = q + 4 * i;
        float v = src[(size_t)r * 512 + c];
        tile[r][c] = v;
        bool nz = (v != 0.f);
        colcnt += nz ? 1.f : 0.f;
        unsigned long long mask = __ballot(nz);
        if (c == 0)
            ws[OFF_NPG + tp * 2048 + b * 512 + g0 + r] = (float)__popcll(mask);
    }
    cc[q][c] = colcnt;
    __syncthreads();
    if (q == 0)
        ws[OFF_NPP + tg * 2048 + b * 512 + p0 + c] =
            cc[0][c] + cc[1][c] + cc[2][c] + cc[3][c];
    // A-frag emission, both sides (R8-verified layout)
    int ri = c & 15, kq = c >> 4;
    unsigned short* afg = (unsigned short*)(ws + OFF_AFRAG);
    unsigned short* afp = afg + 1048576;
    int rt_g = b * 32 + tg * 4 + q;
    int rt_p = b * 32 + tp * 4 + q;
#pragma unroll
    for (int ks2 = 0; ks2 < 2; ++ks2) {
        int ks_g = tp * 2 + ks2;
        int ks_p = tg * 2 + ks2;
        bf16x8 og, op;
#pragma unroll
        for (int i = 0; i < 8; ++i) {
            og[i] = (short)f2bf(tile[q * 16 + ri][ks2 * 32 + kq * 8 + i]);
            op[i] = (short)f2bf(tile[ks2 * 32 + kq * 8 + i][q * 16 + ri]);
        }
        *(bf16x8*)(afg + ((size_t)(rt_g * 16 + ks_g) * 64 + c) * 8) = og;
        *(bf16x8*)(afp + ((size_t)(rt_p * 16 + ks_p) * 64 + c) * 8) = op;
    }
    // ride-along tasks
    int lin = b * 64 + blockIdx.x;
    if (lin < 48) {   // weight pack: 12 mats x 4 ks2
        int mat = lin >> 2, ks2 = lin & 3;
        int side = mat / 6, m = (mat / 3) & 1, layer = mat % 3;
        const float* W = (side ? (m ? Wu_p : Wm_p) : (m ? Wu_g : Wm_g)) + layer * 8192;
        int ftq = t >> 6, lane = t & 63;
        int f = ftq * 16 + (lane & 15);
        int kbase = ks2 * 32 + ((lane >> 4) & 3) * 8;
        bf16x8 oh, ol;
#pragma unroll
        for (int i = 0; i < 8; ++i) {
            float v = W[(kbase + i) * 64 + f];
            unsigned short hi = f2bf(v);
            oh[i] = (short)hi;
            ol[i] = (short)f2bf(v - __uint_as_float((unsigned)hi << 16));
        }
        unsigned short* WF = (unsigned short*)(ws + OFF_WF);
        *(bf16x8*)(WF + (((size_t)(mat * 2 + 0) * 4 + ks2) * 4 + ftq) * 512 + lane * 8) = oh;
        *(bf16x8*)(WF + (((size_t)(mat * 2 + 1) * 4 + ks2) * 4 + ftq) * 512 + lane * 8) = ol;
    } else if (lin == 48 && t < 128) {   // U precompute
        int side = t >> 6, f = t & 63;
        const float* Wee = side ? Wee_p : Wee_g;
        const float* Wef = side ? Wef_p : Wef_g;
        float u = 0.f;
#pragma unroll
        for (int e = 0; e < 63; ++e) u += fmaxf(Wee[e], 0.f) * Wef[e * 64 + f];
        ws[OFF_U + t] = u;
    }
}

// ---------------- K2: fused init + LAYER 0 (rank-1 agg) ----------------
__global__ __launch_bounds__(256) void k_init_l0(float* __restrict__ ws,
        const float* __restrict__ Wi_g, const float* __restrict__ Wi_p,
        const float* __restrict__ Wef_g, const float* __restrict__ Wef_p) {
    __shared__ float normall[2048];
    __shared__ float nopp[512];
    __shared__ float redm[4];
    __shared__ float sred[4][16], wred[4][16];
    __shared__ float s_l[16], w_l[16];
    __shared__ float xe[16][68], xh[16][68], xa[16][68], xm[16][68];
    int bid = blockIdx.x, side = bid >> 7, rt = bid & 127;
    int lr0 = rt * 16, b = rt >> 5;
    int t = threadIdx.x, lane = t & 63, w = t >> 6;
    const float* pown = ws + (side ? OFF_NPP : OFF_NPG);
    const float* popp = ws + (side ? OFF_NPG : OFF_NPP) + b * 512;
#pragma unroll
    for (int i = 0; i < 8; ++i) {
        int r = t + 256 * i;
        float s = 0.f;
#pragma unroll
        for (int j = 0; j < 8; ++j) s += pown[j * 2048 + r];
        normall[r] = s;
    }
#pragma unroll
    for (int i = 0; i < 2; ++i) {
        int r = t + 256 * i;
        float s = 0.f;
#pragma unroll
        for (int j = 0; j < 8; ++j) s += popp[j * 2048 + r];
        nopp[r] = s;
    }
    __syncthreads();
    float m = 0.f;
#pragma unroll
    for (int i = 0; i < 8; ++i) m = fmaxf(m, normall[t + 256 * i]);
    m = wave_max(m);
    if (lane == 0) redm[w] = m;
    const unsigned short* af = (const unsigned short*)(ws + OFF_AFRAG)
                               + (size_t)side * 1048576;
    int kq = lane >> 4;
    float sacc = 0.f, wacc = 0.f;
#pragma unroll
    for (int kk = 0; kk < 4; ++kk) {
        int ks = w * 4 + kk;
        bf16x8 a = *(const bf16x8*)(af + ((size_t)(rt * 16 + ks) * 64 + lane) * 8);
#pragma unroll
        for (int i = 0; i < 8; ++i)
            if (a[i] != 0) {
                float nv = nopp[ks * 32 + kq * 8 + i];
                sacc += nv;
                float av = __uint_as_float((unsigned)(unsigned short)a[i] << 16);
                wacc += av * nv;
            }
    }
    sacc += __shfl_xor(sacc, 16, 64);
    sacc += __shfl_xor(sacc, 32, 64);
    wacc += __shfl_xor(wacc, 16, 64);
    wacc += __shfl_xor(wacc, 32, 64);
    if (lane < 16) { sred[w][lane] = sacc; wred[w][lane] = wacc; }
    __syncthreads();
    float mxs = fmaxf(fmaxf(redm[0], redm[1]), fmaxf(redm[2], redm[3]));
    if (t < 16) {
        s_l[t] = (sred[0][t] + sred[1][t] + sred[2][t] + sred[3][t]) * (1.f / 512.f);
        w_l[t] = (wred[0][t] + wred[1][t] + wred[2][t] + wred[3][t]) * (1.f / 512.f);
    }
    __syncthreads();
    float maxnf = fmaxf(mxs, 1.f);
    const float* Wi_own = side ? Wi_p : Wi_g;
    const float* Wi_opp = side ? Wi_g : Wi_p;
    const float* Wef = side ? Wef_p : Wef_g;
    int ff = lane;
    float Uv = ws[OFF_U + side * 64 + ff];
    float wef63 = Wef[63 * 64 + ff];
    float wiv = Wi_own[ff];
    float wio = fmaxf(Wi_opp[ff], 0.f);
#pragma unroll
    for (int q = 0; q < 4; ++q) {
        int r = w * 4 + q, lr = lr0 + r;
        float norm = normall[lr];
        float nf1 = norm > 0.f ? norm : 1.f;
        float h = fmaxf(norm * (1.f / 512.f) * wiv, 0.f);
        xh[r][ff] = h;
        float A = s_l[r] / nf1;
        float C = norm / maxnf;
        float e = fmaxf(A * Uv + C * wef63, 0.f);
        ws[(side ? OFF_EP : OFF_EG) + (size_t)lr * 64 + ff] = e;
        xe[r][ff] = e;
        xa[r][ff] = w_l[r] * wio / nf1;     // exact rank-1 layer-0 aggregation
    }
    __syncthreads();

    int ft = __builtin_amdgcn_readfirstlane(w);
    const unsigned short* WF = (const unsigned short*)(ws + OFF_WF);
    int mat_msg = (side * 2 + 0) * 3 + 0;
    int mat_upd = (side * 2 + 1) * 3 + 0;
    int ar = lane & 15, koff = ((lane >> 4) & 3) * 8;

    f32x4 mc = {0.f, 0.f, 0.f, 0.f};
#pragma unroll
    for (int ks2 = 0; ks2 < 4; ++ks2) {
        const float* src = (ks2 < 2) ? &xa[ar][ks2 * 32 + koff]
                                     : &xe[ar][(ks2 - 2) * 32 + koff];
        float4 lo4 = *(const float4*)src;
        float4 hi4 = *(const float4*)(src + 4);
        bf16x8 xhf, xlf;
        {
            float xv[8] = {lo4.x, lo4.y, lo4.z, lo4.w, hi4.x, hi4.y, hi4.z, hi4.w};
#pragma unroll
            for (int i = 0; i < 8; ++i) {
                unsigned short hh = f2bf(xv[i]);
                xhf[i] = (short)hh;
                xlf[i] = (short)f2bf(xv[i] - __uint_as_float((unsigned)hh << 16));
            }
        }
        bf16x8 wh = *(const bf16x8*)(WF + (((size_t)(mat_msg * 2 + 0) * 4 + ks2) * 4 + ft) * 512 + lane * 8);
        bf16x8 wl = *(const bf16x8*)(WF + (((size_t)(mat_msg * 2 + 1) * 4 + ks2) * 4 + ft) * 512 + lane * 8);
        mc = __builtin_amdgcn_mfma_f32_16x16x32_bf16(xhf, wh, mc, 0, 0, 0);
        mc = __builtin_amdgcn_mfma_f32_16x16x32_bf16(xlf, wh, mc, 0, 0, 0);
        mc = __builtin_amdgcn_mfma_f32_16x16x32_bf16(xhf, wl, mc, 0, 0, 0);
    }
    {
        int c = lane & 15, rq = (lane >> 4) * 4, f = ft * 16 + c;
#pragma unroll
        for (int j = 0; j < 4; ++j) xm[rq + j][f] = fmaxf(mc[j], 0.f);
    }
    __syncthreads();

    f32x4 uc = {0.f, 0.f, 0.f, 0.f};
#pragma unroll
    for (int ks2 = 0; ks2 < 4; ++ks2) {
        const float* src = (ks2 < 2) ? &xh[ar][ks2 * 32 + koff]
                                     : &xm[ar][(ks2 - 2) * 32 + koff];
        float4 lo4 = *(const float4*)src;
        float4 hi4 = *(const float4*)(src + 4);
        bf16x8 xhf, xlf;
        {
            float xv[8] = {lo4.x, lo4.y, lo4.z, lo4.w, hi4.x, hi4.y, hi4.z, hi4.w};
#pragma unroll
            for (int i = 0; i < 8; ++i) {
                unsigned short hh = f2bf(xv[i]);
                xhf[i] = (short)hh;
                xlf[i] = (short)f2bf(xv[i] - __uint_as_float((unsigned)hh << 16));
            }
        }
        bf16x8 wh = *(const bf16x8*)(WF + (((size_t)(mat_upd * 2 + 0) * 4 + ks2) * 4 + ft) * 512 + lane * 8);
        bf16x8 wl = *(const bf16x8*)(WF + (((size_t)(mat_upd * 2 + 1) * 4 + ks2) * 4 + ft) * 512 + lane * 8);
        uc = __builtin_amdgcn_mfma_f32_16x16x32_bf16(xhf, wh, uc, 0, 0, 0);
        uc = __builtin_amdgcn_mfma_f32_16x16x32_bf16(xlf, wh, uc, 0, 0, 0);
        uc = __builtin_amdgcn_mfma_f32_16x16x32_bf16(xhf, wl, uc, 0, 0, 0);
    }
    {   // relu -> HB f32 + HFB frags
        int c = lane & 15, rq = (lane >> 4) * 4, f = ft * 16 + c;
        int hout = side ? OFF_HB_P : OFF_HB_G;
        unsigned short hi4[4], lo4b[4];
#pragma unroll
        for (int j = 0; j < 4; ++j) {
            float hv = fmaxf(uc[j], 0.f);
            ws[hout + (size_t)(lr0 + rq + j) * 64 + f] = hv;
            unsigned short hh = f2bf(hv);
            hi4[j] = hh;
            lo4b[j] = f2bf(hv - __uint_as_float((unsigned)hh << 16));
        }
        int k0 = (rt & 31) * 16 + rq;
        int ks_h = k0 >> 5;
        int lane2 = (f & 15) | (((k0 >> 3) & 3) << 4);
        size_t fidx = (((size_t)(b * 4 + ft) * 16 + ks_h) * 64 + lane2) * 8 + (k0 & 7);
        unsigned short* hf = (unsigned short*)(ws + OFF_HFB) + (size_t)side * 2 * 262144;
        uint2 vh, vl;
        vh.x = (unsigned)hi4[0] | ((unsigned)hi4[1] << 16);
        vh.y = (unsigned)hi4[2] | ((unsigned)hi4[3] << 16);
        vl.x = (unsigned)lo4b[0] | ((unsigned)lo4b[1] << 16);
        vl.y = (unsigned)lo4b[2] | ((unsigned)lo4b[3] << 16);
        *(uint2*)(hf + fidx) = vh;
        *(uint2*)(hf + 262144 + fidx) = vl;
    }
}

// ---------------- K3: full-MFMA layer; norms re-derived from partials ----------------
__global__ __launch_bounds__(256) void k_layer(float* __restrict__ ws, int layer,
        int hin_g, int hin_p, int hout_g, int hout_p, int fin, int fout, int do_pool) {
    __shared__ float xe[16][68], xh[16][68], xa[16][68], xm[16][68];
    __shared__ float nrm16[16];
    __shared__ float psum[4][64];
    int bid = blockIdx.x, side = bid >> 7, rt = bid & 127;
    int lr0 = rt * 16, b = rt >> 5;
    int t = threadIdx.x, lane = t & 63;
    int ft = __builtin_amdgcn_readfirstlane(t >> 6);

    {   // stage e and h_self tiles + 16 row-norms
        int r = t >> 4, c4 = (t & 15) * 4;
        *(float4*)&xe[r][c4] = *(const float4*)(ws + (side ? OFF_EP : OFF_EG)
                                                + (size_t)(lr0 + r) * 64 + c4);
        *(float4*)&xh[r][c4] = *(const float4*)(ws + (side ? hin_p : hin_g)
                                                + (size_t)(lr0 + r) * 64 + c4);
        if (t < 16) {
            const float* po = ws + (side ? OFF_NPP : OFF_NPG) + lr0 + t;
            float s = 0.f;
#pragma unroll
            for (int j = 0; j < 8; ++j) s += po[j * 2048];
            nrm16[t] = fmaxf(s, 1.f);
        }
    }
    __syncthreads();

    // agg via MFMA
    const unsigned short* af = (const unsigned short*)(ws + OFF_AFRAG)
                               + (size_t)side * 1048576;
    const unsigned short* hfh = (const unsigned short*)(ws + fin)
                                + (size_t)(1 - side) * 2 * 262144;
    const unsigned short* hfl = hfh + 262144;
    f32x4 acc = {0.f, 0.f, 0.f, 0.f};
#pragma unroll
    for (int ks = 0; ks < 16; ++ks) {
        bf16x8 a = *(const bf16x8*)(af + ((size_t)(rt * 16 + ks) * 64 + lane) * 8);
        size_t bi = ((((size_t)b * 4 + ft) * 16 + ks) * 64 + lane) * 8;
        bf16x8 bh = *(const bf16x8*)(hfh + bi);
        bf16x8 bl = *(const bf16x8*)(hfl + bi);
        acc = __builtin_amdgcn_mfma_f32_16x16x32_bf16(a, bh, acc, 0, 0, 0);
        acc = __builtin_amdgcn_mfma_f32_16x16x32_bf16(a, bl, acc, 0, 0, 0);
    }
    {   // normalize -> x_agg
        int c = lane & 15, rq = (lane >> 4) * 4, f = ft * 16 + c;
#pragma unroll
        for (int j = 0; j < 4; ++j)
            xa[rq + j][f] = acc[j] / nrm16[rq + j];
    }
    __syncthreads();

    const unsigned short* WF = (const unsigned short*)(ws + OFF_WF);
    int mat_msg = (side * 2 + 0) * 3 + layer;
    int mat_upd = (side * 2 + 1) * 3 + layer;
    int ar = lane & 15, koff = ((lane >> 4) & 3) * 8;

    // msg GEMM: [agg | e] @ Wm
    f32x4 mc = {0.f, 0.f, 0.f, 0.f};
#pragma unroll
    for (int ks2 = 0; ks2 < 4; ++ks2) {
        const float* src = (ks2 < 2) ? &xa[ar][ks2 * 32 + koff]
                                     : &xe[ar][(ks2 - 2) * 32 + koff];
        float4 lo4 = *(const float4*)src;
        float4 hi4 = *(const float4*)(src + 4);
        bf16x8 xhf, xlf;
        {
            float xv[8] = {lo4.x, lo4.y, lo4.z, lo4.w, hi4.x, hi4.y, hi4.z, hi4.w};
#pragma unroll
            for (int i = 0; i < 8; ++i) {
                unsigned short hh = f2bf(xv[i]);
                xhf[i] = (short)hh;
                xlf[i] = (short)f2bf(xv[i] - __uint_as_float((unsigned)hh << 16));
            }
        }
        bf16x8 wh = *(const bf16x8*)(WF + (((size_t)(mat_msg * 2 + 0) * 4 + ks2) * 4 + ft) * 512 + lane * 8);
        bf16x8 wl = *(const bf16x8*)(WF + (((size_t)(mat_msg * 2 + 1) * 4 + ks2) * 4 + ft) * 512 + lane * 8);
        mc = __builtin_amdgcn_mfma_f32_16x16x32_bf16(xhf, wh, mc, 0, 0, 0);
        mc = __builtin_amdgcn_mfma_f32_16x16x32_bf16(xlf, wh, mc, 0, 0, 0);
        mc = __builtin_amdgcn_mfma_f32_16x16x32_bf16(xhf, wl, mc, 0, 0, 0);
    }
    {
        int c = lane & 15, rq = (lane >> 4) * 4, f = ft * 16 + c;
#pragma unroll
        for (int j = 0; j < 4; ++j) xm[rq + j][f] = fmaxf(mc[j], 0.f);
    }
    __syncthreads();

    // upd GEMM: [h_self | m] @ Wu
    f32x4 uc = {0.f, 0.f, 0.f, 0.f};
#pragma unroll
    for (int ks2 = 0; ks2 < 4; ++ks2) {
        const float* src = (ks2 < 2) ? &xh[ar][ks2 * 32 + koff]
                                     : &xm[ar][(ks2 - 2) * 32 + koff];
        float4 lo4 = *(const float4*)src;
        float4 hi4 = *(const float4*)(src + 4);
        bf16x8 xhf, xlf;
        {
            float xv[8] = {lo4.x, lo4.y, lo4.z, lo4.w, hi4.x, hi4.y, hi4.z, hi4.w};
#pragma unroll
            for (int i = 0; i < 8; ++i) {
                unsigned short hh = f2bf(xv[i]);
                xhf[i] = (short)hh;
                xlf[i] = (short)f2bf(xv[i] - __uint_as_float((unsigned)hh << 16));
            }
        }
        bf16x8 wh = *(const bf16x8*)(WF + (((size_t)(mat_upd * 2 + 0) * 4 + ks2) * 4 + ft) * 512 + lane * 8);
        bf16x8 wl = *(const bf16x8*)(WF + (((size_t)(mat_upd * 2 + 1) * 4 + ks2) * 4 + ft) * 512 + lane * 8);
        uc = __builtin_amdgcn_mfma_f32_16x16x32_bf16(xhf, wh, uc, 0, 0, 0);
        uc = __builtin_amdgcn_mfma_f32_16x16x32_bf16(xlf, wh, uc, 0, 0, 0);
        uc = __builtin_amdgcn_mfma_f32_16x16x32_bf16(xhf, wl, uc, 0, 0, 0);
    }
    {   // relu -> hout f32 + vectorized hfrag; optional pool partial
        int c = lane & 15, rq = (lane >> 4) * 4, f = ft * 16 + c;
        int hout = side ? hout_p : hout_g;
        float s4 = 0.f;
        unsigned short hi4[4], lo4[4];
#pragma unroll
        for (int j = 0; j < 4; ++j) {
            float hv = fmaxf(uc[j], 0.f);
            ws[hout + (size_t)(lr0 + rq + j) * 64 + f] = hv;
            unsigned short hh = f2bf(hv);
            hi4[j] = hh;
            lo4[j] = f2bf(hv - __uint_as_float((unsigned)hh << 16));
            s4 += hv;
        }
        int k0 = (rt & 31) * 16 + rq;
        int ks_h = k0 >> 5;
        int lane2 = (f & 15) | (((k0 >> 3) & 3) << 4);
        size_t fidx = (((size_t)(b * 4 + ft) * 16 + ks_h) * 64 + lane2) * 8 + (k0 & 7);
        unsigned short* hf = (unsigned short*)(ws + fout) + (size_t)side * 2 * 262144;
        uint2 vh, vl;
        vh.x = (unsigned)hi4[0] | ((unsigned)hi4[1] << 16);
        vh.y = (unsigned)hi4[2] | ((unsigned)hi4[3] << 16);
        vl.x = (unsigned)lo4[0] | ((unsigned)lo4[1] << 16);
        vl.y = (unsigned)lo4[2] | ((unsigned)lo4[3] << 16);
        *(uint2*)(hf + fidx) = vh;
        *(uint2*)(hf + 262144 + fidx) = vl;
        if (do_pool) {
            psum[lane >> 4][f] = s4;
            __syncthreads();
            if (t < 64)
                ws[OFF_HPART + bid * 64 + t] =
                    psum[0][t] + psum[1][t] + psum[2][t] + psum[3][t];
        }
    }
}

// ---------------- K4: fused pool + readout. 8 blocks x 256 ----------------
__global__ __launch_bounds__(256) void k_out(const float* __restrict__ Wpg,
                                             const float* __restrict__ Wpp,
                                             const float* __restrict__ Wro,
                                             const float* __restrict__ bro,
                                             const float* __restrict__ ws,
                                             float* __restrict__ out) {
    __shared__ float hp[128];
    __shared__ float c1s;
    int bid = blockIdx.x;
    int row0 = bid * 256, b = row0 >> 9;
    int t = threadIdx.x;
    if (t < 128) {
        int sd = t >> 6, k = t & 63;
        const float* q = ws + OFF_HPART + (size_t)(sd * 128 + b * 32) * 64 + k;
        float s = 0.f;
#pragma unroll
        for (int i = 0; i < 32; ++i) s += q[i * 64];
        hp[t] = s;
    }
    __syncthreads();
    if (t < 64) {
        float vg = 0.f, vp = 0.f;
#pragma unroll 4
        for (int k = 0; k < 64; ++k) {
            vg += (hp[k] * (1.f / 512.f)) * Wpg[k * 64 + t];
            vp += (hp[64 + k] * (1.f / 512.f)) * Wpp[k * 64 + t];
        }
        float hv = fmaxf(vg + vp, 0.f);
        float c = wave_sum(hv * Wro[t]);
        if (t == 0) c1s = c + bro[0];
    }
    __syncthreads();
    int idx = row0 + t;
    const float4* hrow = (const float4*)(ws + OFF_HB_G + (size_t)idx * 64);
    float s = 0.f;
#pragma unroll
    for (int k4 = 0; k4 < 16; ++k4) {
        float4 h4 = hrow[k4];
        s += h4.x * Wro[64 + k4 * 4 + 0];
        s += h4.y * Wro[64 + k4 * 4 + 1];
        s += h4.z * Wro[64 + k4 * 4 + 2];
        s += h4.w * Wro[64 + k4 * 4 + 3];
    }
    out[idx] = c1s + s;
}

extern "C" void kernel_launch(void* const* d_in, const int* in_sizes, int n_in,
                              void* d_out, int out_size, void* d_ws, size_t ws_size,
                              hipStream_t stream) {
    const float* obs   = (const float*)d_in[0];
    const float* Wi_g  = (const float*)d_in[1];
    const float* Wi_p  = (const float*)d_in[2];
    const float* Wee_g = (const float*)d_in[3];
    const float* Wef_g = (const float*)d_in[4];
    const float* Wee_p = (const float*)d_in[5];
    const float* Wef_p = (const float*)d_in[6];
    const float* Wm_g  = (const float*)d_in[7];
    const float* Wu_g  = (const float*)d_in[8];
    const float* Wm_p  = (const float*)d_in[9];
    const float* Wu_p  = (const float*)d_in[10];
    const float* Wpg   = (const float*)d_in[11];
    const float* Wpp   = (const float*)d_in[12];
    const float* Wro   = (const float*)d_in[13];
    const float* bro   = (const float*)d_in[14];
    float* ws  = (float*)d_ws;
    float* out = (float*)d_out;

    k_prep<<<dim3(64, 4), 256, 0, stream>>>(obs, ws, Wm_g, Wu_g, Wm_p, Wu_p,
                                            Wee_g, Wef_g, Wee_p, Wef_p);
    k_init_l0<<<256, 256, 0, stream>>>(ws, Wi_g, Wi_p, Wef_g, Wef_p);

    k_layer<<<256, 256, 0, stream>>>(ws, 1, OFF_HB_G, OFF_HB_P, OFF_HA_G, OFF_HA_P,
                                     OFF_HFB, OFF_HFA, 0);
    k_layer<<<256, 256, 0, stream>>>(ws, 2, OFF_HA_G, OFF_HA_P, OFF_HB_G, OFF_HB_P,
                                     OFF_HFA, OFF_HFB, 1);

    k_out<<<8, 256, 0, stream>>>(Wpg, Wpp, Wro, bro, ws, out);
}